// Round 4
// baseline (328.435 us; speedup 1.0000x reference)
//
#include <hip/hip_runtime.h>
#include <hip/hip_bf16.h>

// LinearSim: out = X @ W.T + Bias  (reference's normalizations cancel exactly).
// M=65536, K=512, N=512, f32 in/out, bf16 MFMA inside.
// R2: latency-bound baseline (MfmaUtil 9%, HBM 37%, all-low) ->
//  - double-buffered LDS, reg-staged prefetch of tile t+1 issued before MFMA
//    of tile t, ONE barrier per K-step (loads in flight during MFMA).
//  - XCD-grouping swizzle: 4 N-sibling blocks of an M-panel -> same XCD,
//    so the shared X panel L2-hits (FETCH was 2x ideal).
//  - nontemporal Out stores (streaming) to keep L2 for X.

typedef __bf16 bf16x8 __attribute__((ext_vector_type(8)));
typedef float  f32x4  __attribute__((ext_vector_type(4)));

constexpr int M_TOK = 65536;
constexpr int K_IN  = 512;
constexpr int N_OUT = 512;

constexpr int BM = 128, BN = 128, BK = 32;
constexpr int PK = BK + 8;      // 40 bf16 = 80 B row stride, 16B-aligned
constexpr int NT = K_IN / BK;   // 16 K-steps

__global__ __launch_bounds__(256, 4)
void linear_sim_kernel(const float* __restrict__ X,
                       const float* __restrict__ W,
                       const float* __restrict__ Bias,
                       float* __restrict__ Out)
{
    __shared__ __bf16 As[2][BM][PK];
    __shared__ __bf16 Bs[2][BN][PK];

    // XCD-aware swizzle: blocks round-robin over 8 XCDs, so give each XCD a
    // contiguous chunk of 256 logical tiles; N-siblings (same mb) then run
    // back-to-back on one XCD and share the X panel via its L2.
    const int d  = blockIdx.x;
    const int o  = (d & 7) * 256 + (d >> 3);   // bijective: 2048 % 8 == 0
    const int nb = o & 3;
    const int mb = o >> 2;
    const int m0 = mb * BM, n0 = nb * BN;

    const int tid  = threadIdx.x;
    const int lane = tid & 63;
    const int wave = tid >> 6;
    const int wm = wave >> 1;        // 2x2 waves, 64x64 each
    const int wn = wave & 1;

    // staging: thread t loads 16 consecutive K-floats of row (t>>1), half (t&1)
    const int srow = tid >> 1;
    const int sk   = (tid & 1) * 16;

    const float* Xp = X + (size_t)(m0 + srow) * K_IN + sk;
    const float* Wp = W + (size_t)(n0 + srow) * K_IN + sk;

    f32x4 acc[16];
    const f32x4 zero = {0.f, 0.f, 0.f, 0.f};
    #pragma unroll
    for (int i = 0; i < 16; ++i) acc[i] = zero;

    const int l15 = lane & 15;
    const int lg  = lane >> 4;

    f32x4 xa[4], wb[4];
    // ---- prologue: tile 0 -> regs -> LDS buf 0 ----
    #pragma unroll
    for (int q = 0; q < 4; ++q) xa[q] = *(const f32x4*)(Xp + q * 4);
    #pragma unroll
    for (int q = 0; q < 4; ++q) wb[q] = *(const f32x4*)(Wp + q * 4);
    #pragma unroll
    for (int h = 0; h < 2; ++h) {
        bf16x8 ta, tb;
        #pragma unroll
        for (int q = 0; q < 2; ++q)
            #pragma unroll
            for (int e = 0; e < 4; ++e) {
                ta[q * 4 + e] = (__bf16)xa[h * 2 + q][e];
                tb[q * 4 + e] = (__bf16)wb[h * 2 + q][e];
            }
        *(bf16x8*)&As[0][srow][sk + h * 8] = ta;
        *(bf16x8*)&Bs[0][srow][sk + h * 8] = tb;
    }
    __syncthreads();

    int cur = 0;
    for (int t = 0; t < NT; ++t) {
        const bool pf = (t + 1 < NT);
        // ---- issue next tile's global loads FIRST (latency hides under MFMA) ----
        if (pf) {
            const int k0 = (t + 1) * BK;
            #pragma unroll
            for (int q = 0; q < 4; ++q) xa[q] = *(const f32x4*)(Xp + k0 + q * 4);
            #pragma unroll
            for (int q = 0; q < 4; ++q) wb[q] = *(const f32x4*)(Wp + k0 + q * 4);
        }

        // ---- fragments from buf[cur] + MFMA ----
        bf16x8 af[4], bfr[4];
        #pragma unroll
        for (int i = 0; i < 4; ++i)
            af[i] = *(const bf16x8*)&As[cur][wm * 64 + i * 16 + l15][lg * 8];
        #pragma unroll
        for (int i = 0; i < 4; ++i)
            bfr[i] = *(const bf16x8*)&Bs[cur][wn * 64 + i * 16 + l15][lg * 8];

        #pragma unroll
        for (int mi = 0; mi < 4; ++mi)
            #pragma unroll
            for (int ni = 0; ni < 4; ++ni)
                acc[mi * 4 + ni] = __builtin_amdgcn_mfma_f32_16x16x32_bf16(
                    af[mi], bfr[ni], acc[mi * 4 + ni], 0, 0, 0);

        // ---- convert + write next tile into buf[cur^1] (waits vmcnt here) ----
        if (pf) {
            #pragma unroll
            for (int h = 0; h < 2; ++h) {
                bf16x8 ta, tb;
                #pragma unroll
                for (int q = 0; q < 2; ++q)
                    #pragma unroll
                    for (int e = 0; e < 4; ++e) {
                        ta[q * 4 + e] = (__bf16)xa[h * 2 + q][e];
                        tb[q * 4 + e] = (__bf16)wb[h * 2 + q][e];
                    }
                *(bf16x8*)&As[cur ^ 1][srow][sk + h * 8] = ta;
                *(bf16x8*)&Bs[cur ^ 1][srow][sk + h * 8] = tb;
            }
        }
        __syncthreads();
        cur ^= 1;
    }

    // ---- epilogue: C/D layout col = lane&15, row = (lane>>4)*4 + reg ----
    #pragma unroll
    for (int ni = 0; ni < 4; ++ni) {
        const int col = n0 + wn * 64 + ni * 16 + l15;
        const float bv = Bias[col];
        #pragma unroll
        for (int mi = 0; mi < 4; ++mi) {
            const int row0 = m0 + wm * 64 + mi * 16 + lg * 4;
            f32x4 a = acc[mi * 4 + ni];
            #pragma unroll
            for (int r = 0; r < 4; ++r)
                __builtin_nontemporal_store(a[r] + bv,
                    &Out[(size_t)(row0 + r) * N_OUT + col]);
        }
    }
}

extern "C" void kernel_launch(void* const* d_in, const int* in_sizes, int n_in,
                              void* d_out, int out_size, void* d_ws, size_t ws_size,
                              hipStream_t stream) {
    const float* X    = (const float*)d_in[0];
    const float* W    = (const float*)d_in[1];
    const float* Bias = (const float*)d_in[2];
    float* Out        = (float*)d_out;

    dim3 grid((M_TOK / BM) * (N_OUT / BN));   // 2048 blocks
    linear_sim_kernel<<<grid, dim3(256), 0, stream>>>(X, W, Bias, Out);
}